// Round 7
// baseline (187.373 us; speedup 1.0000x reference)
//
#include <hip/hip_runtime.h>

typedef unsigned short u16;
typedef short bf16x8 __attribute__((ext_vector_type(8)));
typedef float f32x4 __attribute__((ext_vector_type(4)));
typedef u16 u16x8 __attribute__((ext_vector_type(8)));
typedef u16 u16x4 __attribute__((ext_vector_type(4)));

#define B_ 4
#define S_ 4096
#define E_ 1024
#define H_ 16
#define D_ 64
#define M_ 16384
#define N_ 3072
#define K_ 1024

__device__ __forceinline__ u16 f2b(float f) {
    unsigned x = __builtin_bit_cast(unsigned, f);
    return (u16)((x + 0x7fffu + ((x >> 16) & 1u)) >> 16);   // RNE
}
__device__ __forceinline__ float b2f(u16 u) {
    unsigned x = ((unsigned)u) << 16;
    return __builtin_bit_cast(float, x);
}
__device__ __forceinline__ float phi_f(float x) { return x > 0.f ? x + 1.f : __expf(x); }

__device__ __forceinline__ void gload16(const void* g, void* l) {
    __builtin_amdgcn_global_load_lds((const __attribute__((address_space(1))) void*)g,
                                     (__attribute__((address_space(3))) void*)l, 16, 0, 0);
}

#define MEMFENCE asm volatile("" ::: "memory")
#define BAR { MEMFENCE; __builtin_amdgcn_s_barrier(); MEMFENCE; }
#define LGKM0 { asm volatile("s_waitcnt lgkmcnt(0)" ::: "memory"); \
                __builtin_amdgcn_sched_barrier(0); }
#define VMCNT(n) asm volatile("s_waitcnt vmcnt(" #n ")" ::: "memory")

// ---------------- kernel 1: fp32 -> bf16 convert ----------------
__global__ void cvt_bf16(const float* __restrict__ in, u16* __restrict__ out, int n8) {
    int stride = gridDim.x * blockDim.x;
    for (int i = blockIdx.x * blockDim.x + threadIdx.x; i < n8; i += stride) {
        const float4* p = (const float4*)(in + (size_t)i * 8);
        float4 a = p[0], b = p[1];
        u16x8 o;
        o[0] = f2b(a.x); o[1] = f2b(a.y); o[2] = f2b(a.z); o[3] = f2b(a.w);
        o[4] = f2b(b.x); o[5] = f2b(b.y); o[6] = f2b(b.z); o[7] = f2b(b.w);
        *(u16x8*)(out + (size_t)i * 8) = o;
    }
}

// ---------------- shared 256^2-tile 8-phase GEMM machinery (R5/R6) ----------------

#define RD_A(BO, MI0) { _Pragma("unroll") for (int m_ = 0; m_ < 4; ++m_) { \
    av[m_][0] = *(const bf16x8*)(aB + (BO) + (MI0 + m_) * 2048 + pc0); \
    av[m_][1] = *(const bf16x8*)(aB + (BO) + (MI0 + m_) * 2048 + pc1); } }

#define RD_B01(BO) { _Pragma("unroll") for (int n_ = 0; n_ < 2; ++n_) { \
    b01[n_][0] = *(const bf16x8*)(bB + (BO) + n_ * 2048 + pc0); \
    b01[n_][1] = *(const bf16x8*)(bB + (BO) + n_ * 2048 + pc1); } }

#define RD_B23(BO) { _Pragma("unroll") for (int n_ = 0; n_ < 2; ++n_) { \
    b23[n_][0] = *(const bf16x8*)(bB + (BO) + (2 + n_) * 2048 + pc0); \
    b23[n_][1] = *(const bf16x8*)(bB + (BO) + (2 + n_) * 2048 + pc1); } }

#define ST_A(TT, HI, BO) { \
    gload16(gA + (size_t)((HI) * 64) * K_ + (TT) * 64, lds + (BO) + (HI) * 8192 + t16); \
    gload16(gA + (size_t)((HI) * 64 + 128) * K_ + (TT) * 64, lds + (BO) + 16384 + (HI) * 8192 + t16); }

#define ST_B(TT, PR, BO) { \
    gload16(gB + (size_t)((PR) * 128) * K_ + (TT) * 64, lds + (BO) + 32768 + (PR) * 16384 + t16); \
    gload16(gB + (size_t)((PR) * 128 + 64) * K_ + (TT) * 64, lds + (BO) + 32768 + (PR) * 16384 + 8192 + t16); }

#define MM16(MI0, NI0, BV) { __builtin_amdgcn_s_setprio(1); \
    _Pragma("unroll") for (int m_ = 0; m_ < 4; ++m_) \
    _Pragma("unroll") for (int n_ = 0; n_ < 2; ++n_) \
    _Pragma("unroll") for (int h_ = 0; h_ < 2; ++h_) \
        acc[(MI0) + m_][(NI0) + n_] = __builtin_amdgcn_mfma_f32_16x16x32_bf16( \
            av[m_][h_], BV[n_][h_], acc[(MI0) + m_][(NI0) + n_], 0, 0, 0); \
    __builtin_amdgcn_s_setprio(0); }

__device__ __forceinline__ void run_tile(
    const u16* gA, const u16* gB, char* lds, int t16,
    const char* aB, const char* bB, int pc0, int pc1, f32x4 (&acc)[8][4])
{
    bf16x8 av[4][2], b01[2][2], b23[2][2];
    ST_A(0, 0, 0); ST_B(0, 0, 0); ST_B(0, 1, 0); ST_A(0, 1, 0);
    ST_A(1, 0, 65536); ST_B(1, 0, 65536);
    VMCNT(4);
    __builtin_amdgcn_s_barrier();
    MEMFENCE;
#pragma unroll 1
    for (int kt = 0; kt < 16; kt += 2) {
        int tp2 = kt + 2 < 16 ? kt + 2 : 15;
        int tp3 = kt + 3 < 16 ? kt + 3 : 15;
        RD_A(0, 0); RD_B01(0); ST_A(kt + 1, 1, 65536); BAR; LGKM0; MM16(0, 0, b01);
        RD_B23(0);  ST_B(kt + 1, 1, 65536);            BAR; LGKM0; MM16(0, 2, b23);
        RD_A(0, 4); ST_A(tp2, 0, 0);                   BAR; LGKM0; MM16(4, 2, b23);
        ST_B(tp2, 0, 0); VMCNT(4);                     BAR; LGKM0; MM16(4, 0, b01);
        RD_A(65536, 0); RD_B01(65536); ST_A(tp2, 1, 0); BAR; LGKM0; MM16(0, 0, b01);
        RD_B23(65536);  ST_B(tp2, 1, 0);                BAR; LGKM0; MM16(0, 2, b23);
        RD_A(65536, 4); ST_A(tp3, 0, 65536);            BAR; LGKM0; MM16(4, 2, b23);
        ST_B(tp3, 0, 65536); VMCNT(4);                  BAR; LGKM0; MM16(4, 0, b01);
    }
    VMCNT(0);
    __builtin_amdgcn_s_barrier();
    MEMFENCE;
}

// ---------------- kernel 2: V + K GEMM tiles + in-block kv/ksum partials ----------------
__global__ __launch_bounds__(512, 2) void gemm_vk(
    const u16* __restrict__ Abf, const u16* __restrict__ Wbf,
    const float* __restrict__ bias, const float* __restrict__ mask,
    u16* VT, float* __restrict__ KVP, float* __restrict__ KSP)
{
    __shared__ __align__(16) char lds[131072];

    int wg  = blockIdx.x;                 // 256 blocks, 1/CU
    int xcd = wg & 7, ii = wg >> 3;
    int tm  = xcd * 8 + (ii >> 2);
    int g   = ii & 3;
    int m0  = tm << 8;
    int b   = tm >> 4;
    int s0  = (tm & 15) << 8;

    int t = threadIdx.x;
    int l = t & 63, wid = t >> 6;
    int wr = wid >> 2, wc = wid & 3;
    int lg = l >> 4, lr = l & 15;

    int srow  = t >> 3;
    int scolE = ((t & 7) ^ (srow & 7)) << 3;
    int t16   = t * 16;

    const u16* gA = Abf + (size_t)(m0 + srow) * K_ + scolE;
    const char* aB = lds + (wr * 128 + lr) * 128;
    const char* bB = lds + 32768 + (wc * 64 + lr) * 128;
    int pc0 = (lg * 16) ^ ((lr & 7) << 4);
    int pc1 = pc0 ^ 64;

    // ===== tile V =====
    {
        int n0 = 2048 + g * 256;
        const u16* gB = Wbf + (size_t)(n0 + srow) * K_ + scolE;
        f32x4 acc[8][4] = {};
        run_tile(gA, gB, lds, t16, aB, bB, pc0, pc1, acc);
        float bv[4];
#pragma unroll
        for (int ni = 0; ni < 4; ++ni) bv[ni] = bias[n0 + wc * 64 + ni * 16 + lr];
        int h = g * 4 + wc;
#pragma unroll
        for (int mi = 0; mi < 8; ++mi) {
            int sbase = s0 + wr * 128 + mi * 16 + lg * 4;
#pragma unroll
            for (int ni = 0; ni < 4; ++ni) {
                u16x4 o;
#pragma unroll
                for (int j = 0; j < 4; ++j) o[j] = f2b(acc[mi][ni][j] + bv[ni]);
                int d = ni * 16 + lr;
                *(u16x4*)(VT + ((size_t)((b * H_ + h) * D_ + d)) * S_ + sbase) = o;
            }
        }
    }

    // ===== tile K -> kk in LDS =====
    {
        int n0 = 1024 + g * 256;
        const u16* gB = Wbf + (size_t)(n0 + srow) * K_ + scolE;
        f32x4 acc[8][4] = {};
        run_tile(gA, gB, lds, t16, aB, bB, pc0, pc1, acc);
        float bv[4];
#pragma unroll
        for (int ni = 0; ni < 4; ++ni) bv[ni] = bias[n0 + wc * 64 + ni * 16 + lr];
        // kk LDS: [head=wc][d][s], byte = wc*32768 + d*512 + (s*2 ^ ((d&7)<<4))
#pragma unroll
        for (int mi = 0; mi < 8; ++mi) {
            int sl0 = wr * 128 + mi * 16 + lg * 4;
            float mk[4];
#pragma unroll
            for (int j = 0; j < 4; ++j) mk[j] = mask[m0 + sl0 + j];
#pragma unroll
            for (int ni = 0; ni < 4; ++ni) {
                int d = ni * 16 + lr;
                u16x4 o;
#pragma unroll
                for (int j = 0; j < 4; ++j)
                    o[j] = f2b(phi_f((acc[mi][ni][j] + bv[ni]) * mk[j]));
                *(u16x4*)(lds + wc * 32768 + d * 512 + ((sl0 * 2) ^ ((d & 7) << 4))) = o;
            }
        }
    }
    __syncthreads();

    // ===== kv + ksum partials (kk from LDS, v from VT just written) =====
    {
        int head = wid & 3, mh = wid >> 2;
        int bh = b * 16 + g * 4 + head;
        f32x4 akv[2][4] = {};
        const u16* vbase = VT + ((size_t)(bh * 64 + mh * 32 + lr)) * S_ + s0;
#pragma unroll
        for (int ks = 0; ks < 8; ++ks) {
            bf16x8 vf[2];
#pragma unroll
            for (int mi = 0; mi < 2; ++mi)
                vf[mi] = *(const bf16x8*)(vbase + (size_t)mi * 16 * S_ + ks * 32 + lg * 8);
#pragma unroll
            for (int ni = 0; ni < 4; ++ni) {
                int dd = ni * 16 + lr;
                bf16x8 kf = *(const bf16x8*)(lds + head * 32768 + dd * 512 +
                                             ((ks * 64 + lg * 16) ^ ((dd & 7) << 4)));
                akv[0][ni] = __builtin_amdgcn_mfma_f32_16x16x32_bf16(vf[0], kf, akv[0][ni], 0, 0, 0);
                akv[1][ni] = __builtin_amdgcn_mfma_f32_16x16x32_bf16(vf[1], kf, akv[1][ni], 0, 0, 0);
            }
        }
        float* kvp = KVP + ((size_t)(tm & 15) * 64 + bh) * 4096;
#pragma unroll
        for (int mi = 0; mi < 2; ++mi)
#pragma unroll
            for (int ni = 0; ni < 4; ++ni)
#pragma unroll
                for (int j = 0; j < 4; ++j)
                    kvp[(mh * 32 + mi * 16 + lg * 4 + j) * 64 + ni * 16 + lr] = akv[mi][ni][j];
        int hd = t >> 7, dd2 = (t >> 1) & 63, hf = t & 1;
        float ksm = 0.f;
#pragma unroll
        for (int i = 0; i < 16; ++i) {
            bf16x8 kk8 = *(const bf16x8*)(lds + hd * 32768 + dd2 * 512 +
                                          ((hf * 256 + i * 16) ^ ((dd2 & 7) << 4)));
#pragma unroll
            for (int e = 0; e < 8; ++e) ksm += b2f((u16)kk8[e]);
        }
        ksm += __shfl_xor(ksm, 1);
        if (!hf) KSP[(tm & 15) * 4096 + (b * 16 + g * 4 + hd) * 64 + dd2] = ksm;
    }
}

// ---------------- kernel 3: reduce partials -> KVB bf16 [bh][80][64] pre-swizzled ----------------
// rows 0-63 = kv[m][d], row 64 = ksum[d], rows 65-79 = 0.  u16 index swizzle:
// idx = d ^ ((m&7)<<3)  (byte (d*2)^((m&7)<<4)) so gemm_qattn can stage linearly.
__global__ void reduce_kvb(const float* __restrict__ KVP, const float* __restrict__ KSP,
                           u16* __restrict__ KVB)
{
    int bh = blockIdx.x;            // 64
    int t = threadIdx.x;            // 256
    int d = t & 63, mg = t >> 6;
#pragma unroll 1
    for (int i = 0; i < 16; ++i) {
        int m = mg * 16 + i;
        float s = 0.f;
#pragma unroll
        for (int c = 0; c < 16; ++c)
            s += KVP[((size_t)c * 64 + bh) * 4096 + m * 64 + d];
        KVB[((size_t)bh * 80 + m) * 64 + (d ^ ((m & 7) << 3))] = f2b(s);
    }
    if (mg == 0) {
        float s = 0.f;
#pragma unroll
        for (int c = 0; c < 16; ++c) s += KSP[c * 4096 + bh * 64 + d];
        KVB[((size_t)bh * 80 + 64) * 64 + d] = f2b(s);   // m=64 -> m&7==0
    }
    for (int m = 65 + mg; m < 80; m += 4)
        KVB[((size_t)bh * 80 + m) * 64 + (d ^ ((m & 7) << 3))] = 0;
}

// ---------------- kernel 4: Q GEMM + fused attention epilogue ----------------
// Q-tile acc stays in registers; kq -> LDS (XOR-swizzled) in two 128-row
// rounds; attn MFMA vs KVB (staged linearly, pre-swizzled); den = ksum column;
// divide; fp32 store.  KQ HBM buffer and attn_out kernel are gone.
__global__ __launch_bounds__(512, 2) void gemm_qattn(
    const u16* __restrict__ Abf, const u16* __restrict__ Wbf,
    const float* __restrict__ bias, const u16* __restrict__ KVB,
    float* __restrict__ Out)
{
    __shared__ __align__(16) char lds[131072];

    int wg  = blockIdx.x;
    int xcd = wg & 7, ii = wg >> 3;
    int tm  = xcd * 8 + (ii >> 2);
    int g   = ii & 3;
    int m0  = tm << 8;
    int b   = tm >> 4;

    int t = threadIdx.x;
    int l = t & 63, wid = t >> 6;
    int wr = wid >> 2, wc = wid & 3;
    int lg = l >> 4, lr = l & 15;

    int srow  = t >> 3;
    int scolE = ((t & 7) ^ (srow & 7)) << 3;
    int t16   = t * 16;

    const u16* gA = Abf + (size_t)(m0 + srow) * K_ + scolE;
    const char* aB = lds + (wr * 128 + lr) * 128;
    const char* bB = lds + 32768 + (wc * 64 + lr) * 128;
    int pc0 = (lg * 16) ^ ((lr & 7) << 4);
    int pc1 = pc0 ^ 64;

    int n0 = g * 256;
    const u16* gB = Wbf + (size_t)(n0 + srow) * K_ + scolE;
    f32x4 acc[8][4] = {};
    run_tile(gA, gB, lds, t16, aB, bB, pc0, pc1, acc);

    // stage kv for 4 heads (40960 B) into lds[0..40960); overlap with phi VALU
    {
        const u16* kvbg = KVB + (size_t)(b * 16 + g * 4) * 80 * 64;
#pragma unroll
        for (int i = 0; i < 5; ++i)
            gload16(kvbg + i * 4096 + t * 8, lds + i * 8192 + t16);
    }
    float bv[4];
#pragma unroll
    for (int ni = 0; ni < 4; ++ni) bv[ni] = bias[n0 + wc * 64 + ni * 16 + lr];
#pragma unroll
    for (int mi = 0; mi < 8; ++mi)
#pragma unroll
        for (int ni = 0; ni < 4; ++ni)
#pragma unroll
            for (int j = 0; j < 4; ++j)
                acc[mi][ni][j] = phi_f(acc[mi][ni][j] + bv[ni]);
    VMCNT(0);
    __syncthreads();

    // two rounds of 128 s-rows: kq -> LDS [s_loc][head][d] at offset 40960
#pragma unroll
    for (int r = 0; r < 2; ++r) {
        __syncthreads();                  // prior round's reads complete
        if (wr == r) {
#pragma unroll
            for (int mi = 0; mi < 8; ++mi)
#pragma unroll
                for (int j = 0; j < 4; ++j) {
                    int sl = mi * 16 + lg * 4 + j;
                    int swz = (sl & 7) << 4;
#pragma unroll
                    for (int ni = 0; ni < 4; ++ni) {
                        int d2 = (ni * 16 + lr) * 2;
                        *(u16*)(lds + 40960 + sl * 512 + wc * 128 + (d2 ^ swz)) =
                            f2b(acc[mi][ni][j]);
                    }
                }
        }
        __syncthreads();

        f32x4 a2[4][5] = {};
#pragma unroll
        for (int kh = 0; kh < 2; ++kh) {
            bf16x8 af[4];
#pragma unroll
            for (int mi2 = 0; mi2 < 4; ++mi2) {
                int sl = wr * 64 + mi2 * 16 + lr;
                af[mi2] = *(const bf16x8*)(lds + 40960 + sl * 512 + wc * 128 +
                                           ((kh * 64 + lg * 16) ^ ((sl & 7) << 4)));
            }
#pragma unroll
            for (int ni2 = 0; ni2 < 5; ++ni2) {
                int m = ni2 * 16 + lr;
                bf16x8 bf_ = *(const bf16x8*)(lds + wc * 10240 + m * 128 +
                                              ((kh * 64 + lg * 16) ^ ((m & 7) << 4)));
#pragma unroll
                for (int mi2 = 0; mi2 < 4; ++mi2)
                    a2[mi2][ni2] = __builtin_amdgcn_mfma_f32_16x16x32_bf16(
                        af[mi2], bf_, a2[mi2][ni2], 0, 0, 0);
            }
        }
        // den (ksum column, m=64 -> lane lr==0 of ni2=4), divide, store fp32
#pragma unroll
        for (int mi2 = 0; mi2 < 4; ++mi2)
#pragma unroll
            for (int j = 0; j < 4; ++j) {
                float den = __shfl(a2[mi2][4][j], l & 48);
                float z = 1.f / (den + 1e-6f);
                int sg = (tm & 15) * 256 + r * 128 + wr * 64 + mi2 * 16 + lg * 4 + j;
                float* op = Out + ((size_t)b * S_ + sg) * E_ + g * 256 + wc * 64;
#pragma unroll
                for (int ni2 = 0; ni2 < 4; ++ni2)
                    op[ni2 * 16 + lr] = a2[mi2][ni2][j] * z;
            }
    }
}

extern "C" void kernel_launch(void* const* d_in, const int* in_sizes, int n_in,
                              void* d_out, int out_size, void* d_ws, size_t ws_size,
                              hipStream_t stream)
{
    const float* inputs = (const float*)d_in[0];
    const float* mask   = (const float*)d_in[1];
    const float* w_qkv  = (const float*)d_in[2];
    const float* b_qkv  = (const float*)d_in[3];

    u16* Abf = (u16*)d_ws;                          // 16777216 bf16 (32 MB)
    u16* Wbf = Abf + (size_t)M_ * K_;               // 3145728 bf16 (6 MB)
    float* KVP = (float*)(Wbf + (size_t)N_ * K_);   // 16*64*4096 f32 (16 MB)
    float* KSP = KVP + 16 * 64 * 4096;              // 16*4096 f32
    u16* KVB   = (u16*)(KSP + 16 * 4096);           // 64*80*64 bf16 (640 KB)

    // V^T lives in d_out (bf16, 32 MB), consumed inside gemm_vk only;
    // gemm_qattn overwrites d_out with the final fp32 output.
    u16* VT = (u16*)d_out;

    cvt_bf16<<<2048, 256, 0, stream>>>(inputs, Abf, M_ * K_ / 8);
    cvt_bf16<<<768, 256, 0, stream>>>(w_qkv, Wbf, N_ * K_ / 8);
    gemm_vk<<<256, 512, 0, stream>>>(Abf, Wbf, b_qkv, mask, VT, KVP, KSP);
    reduce_kvb<<<64, 256, 0, stream>>>(KVP, KSP, KVB);
    gemm_qattn<<<256, 512, 0, stream>>>(Abf, Wbf, b_qkv, KVB, (float*)d_out);
}

// Round 8
// 161.467 us; speedup vs baseline: 1.1604x; 1.1604x over previous
//
#include <hip/hip_runtime.h>

typedef unsigned short u16;
typedef short bf16x8 __attribute__((ext_vector_type(8)));
typedef float f32x4 __attribute__((ext_vector_type(4)));
typedef u16 u16x8 __attribute__((ext_vector_type(8)));
typedef u16 u16x4 __attribute__((ext_vector_type(4)));

#define B_ 4
#define S_ 4096
#define E_ 1024
#define H_ 16
#define D_ 64
#define M_ 16384
#define N_ 3072
#define K_ 1024

__device__ __forceinline__ u16 f2b(float f) {
    unsigned x = __builtin_bit_cast(unsigned, f);
    return (u16)((x + 0x7fffu + ((x >> 16) & 1u)) >> 16);   // RNE
}
__device__ __forceinline__ float b2f(u16 u) {
    unsigned x = ((unsigned)u) << 16;
    return __builtin_bit_cast(float, x);
}
__device__ __forceinline__ float phi_f(float x) { return x > 0.f ? x + 1.f : __expf(x); }

__device__ __forceinline__ void gload16(const void* g, void* l) {
    __builtin_amdgcn_global_load_lds((const __attribute__((address_space(1))) void*)g,
                                     (__attribute__((address_space(3))) void*)l, 16, 0, 0);
}

#define MEMFENCE asm volatile("" ::: "memory")
#define BAR { MEMFENCE; __builtin_amdgcn_s_barrier(); MEMFENCE; }
#define LGKM0 { asm volatile("s_waitcnt lgkmcnt(0)" ::: "memory"); \
                __builtin_amdgcn_sched_barrier(0); }
#define VMCNT(n) asm volatile("s_waitcnt vmcnt(" #n ")" ::: "memory")

// ---------------- kernel 1: fp32 -> bf16 convert ----------------
__global__ void cvt_bf16(const float* __restrict__ in, u16* __restrict__ out, int n8) {
    int stride = gridDim.x * blockDim.x;
    for (int i = blockIdx.x * blockDim.x + threadIdx.x; i < n8; i += stride) {
        const float4* p = (const float4*)(in + (size_t)i * 8);
        float4 a = p[0], b = p[1];
        u16x8 o;
        o[0] = f2b(a.x); o[1] = f2b(a.y); o[2] = f2b(a.z); o[3] = f2b(a.w);
        o[4] = f2b(b.x); o[5] = f2b(b.y); o[6] = f2b(b.z); o[7] = f2b(b.w);
        *(u16x8*)(out + (size_t)i * 8) = o;
    }
}

// ---------------- shared 256^2-tile 8-phase GEMM machinery (R5/R6) ----------------

#define RD_A(BO, MI0) { _Pragma("unroll") for (int m_ = 0; m_ < 4; ++m_) { \
    av[m_][0] = *(const bf16x8*)(aB + (BO) + (MI0 + m_) * 2048 + pc0); \
    av[m_][1] = *(const bf16x8*)(aB + (BO) + (MI0 + m_) * 2048 + pc1); } }

#define RD_B01(BO) { _Pragma("unroll") for (int n_ = 0; n_ < 2; ++n_) { \
    b01[n_][0] = *(const bf16x8*)(bB + (BO) + n_ * 2048 + pc0); \
    b01[n_][1] = *(const bf16x8*)(bB + (BO) + n_ * 2048 + pc1); } }

#define RD_B23(BO) { _Pragma("unroll") for (int n_ = 0; n_ < 2; ++n_) { \
    b23[n_][0] = *(const bf16x8*)(bB + (BO) + (2 + n_) * 2048 + pc0); \
    b23[n_][1] = *(const bf16x8*)(bB + (BO) + (2 + n_) * 2048 + pc1); } }

#define ST_A(TT, HI, BO) { \
    gload16(gA + (size_t)((HI) * 64) * K_ + (TT) * 64, lds + (BO) + (HI) * 8192 + t16); \
    gload16(gA + (size_t)((HI) * 64 + 128) * K_ + (TT) * 64, lds + (BO) + 16384 + (HI) * 8192 + t16); }

#define ST_B(TT, PR, BO) { \
    gload16(gB + (size_t)((PR) * 128) * K_ + (TT) * 64, lds + (BO) + 32768 + (PR) * 16384 + t16); \
    gload16(gB + (size_t)((PR) * 128 + 64) * K_ + (TT) * 64, lds + (BO) + 32768 + (PR) * 16384 + 8192 + t16); }

#define MM16(MI0, NI0, BV) { __builtin_amdgcn_s_setprio(1); \
    _Pragma("unroll") for (int m_ = 0; m_ < 4; ++m_) \
    _Pragma("unroll") for (int n_ = 0; n_ < 2; ++n_) \
    _Pragma("unroll") for (int h_ = 0; h_ < 2; ++h_) \
        acc[(MI0) + m_][(NI0) + n_] = __builtin_amdgcn_mfma_f32_16x16x32_bf16( \
            av[m_][h_], BV[n_][h_], acc[(MI0) + m_][(NI0) + n_], 0, 0, 0); \
    __builtin_amdgcn_s_setprio(0); }

__device__ __forceinline__ void run_tile(
    const u16* gA, const u16* gB, char* lds, int t16,
    const char* aB, const char* bB, int pc0, int pc1, f32x4 (&acc)[8][4])
{
    bf16x8 av[4][2], b01[2][2], b23[2][2];
    ST_A(0, 0, 0); ST_B(0, 0, 0); ST_B(0, 1, 0); ST_A(0, 1, 0);
    ST_A(1, 0, 65536); ST_B(1, 0, 65536);
    VMCNT(4);
    __builtin_amdgcn_s_barrier();
    MEMFENCE;
#pragma unroll 1
    for (int kt = 0; kt < 16; kt += 2) {
        int tp2 = kt + 2 < 16 ? kt + 2 : 15;
        int tp3 = kt + 3 < 16 ? kt + 3 : 15;
        RD_A(0, 0); RD_B01(0); ST_A(kt + 1, 1, 65536); BAR; LGKM0; MM16(0, 0, b01);
        RD_B23(0);  ST_B(kt + 1, 1, 65536);            BAR; LGKM0; MM16(0, 2, b23);
        RD_A(0, 4); ST_A(tp2, 0, 0);                   BAR; LGKM0; MM16(4, 2, b23);
        ST_B(tp2, 0, 0); VMCNT(4);                     BAR; LGKM0; MM16(4, 0, b01);
        RD_A(65536, 0); RD_B01(65536); ST_A(tp2, 1, 0); BAR; LGKM0; MM16(0, 0, b01);
        RD_B23(65536);  ST_B(tp2, 1, 0);                BAR; LGKM0; MM16(0, 2, b23);
        RD_A(65536, 4); ST_A(tp3, 0, 65536);            BAR; LGKM0; MM16(4, 2, b23);
        ST_B(tp3, 0, 65536); VMCNT(4);                  BAR; LGKM0; MM16(4, 0, b01);
    }
    VMCNT(0);
    __builtin_amdgcn_s_barrier();
    MEMFENCE;
}

// ---------------- kernel 2: V + K GEMM tiles + in-block kv/ksum partials ----------------
__global__ __launch_bounds__(512, 2) void gemm_vk(
    const u16* __restrict__ Abf, const u16* __restrict__ Wbf,
    const float* __restrict__ bias, const float* __restrict__ mask,
    u16* VT, float* __restrict__ KVP, float* __restrict__ KSP)
{
    __shared__ __align__(16) char lds[131072];

    int wg  = blockIdx.x;                 // 256 blocks, 1/CU
    int xcd = wg & 7, ii = wg >> 3;
    int tm  = xcd * 8 + (ii >> 2);
    int g   = ii & 3;
    int m0  = tm << 8;
    int b   = tm >> 4;
    int s0  = (tm & 15) << 8;

    int t = threadIdx.x;
    int l = t & 63, wid = t >> 6;
    int wr = wid >> 2, wc = wid & 3;
    int lg = l >> 4, lr = l & 15;

    int srow  = t >> 3;
    int scolE = ((t & 7) ^ (srow & 7)) << 3;
    int t16   = t * 16;

    const u16* gA = Abf + (size_t)(m0 + srow) * K_ + scolE;
    const char* aB = lds + (wr * 128 + lr) * 128;
    const char* bB = lds + 32768 + (wc * 64 + lr) * 128;
    int pc0 = (lg * 16) ^ ((lr & 7) << 4);
    int pc1 = pc0 ^ 64;

    // ===== tile V =====
    {
        int n0 = 2048 + g * 256;
        const u16* gB = Wbf + (size_t)(n0 + srow) * K_ + scolE;
        f32x4 acc[8][4] = {};
        run_tile(gA, gB, lds, t16, aB, bB, pc0, pc1, acc);
        float bv[4];
#pragma unroll
        for (int ni = 0; ni < 4; ++ni) bv[ni] = bias[n0 + wc * 64 + ni * 16 + lr];
        int h = g * 4 + wc;
#pragma unroll
        for (int mi = 0; mi < 8; ++mi) {
            int sbase = s0 + wr * 128 + mi * 16 + lg * 4;
#pragma unroll
            for (int ni = 0; ni < 4; ++ni) {
                u16x4 o;
#pragma unroll
                for (int j = 0; j < 4; ++j) o[j] = f2b(acc[mi][ni][j] + bv[ni]);
                int d = ni * 16 + lr;
                *(u16x4*)(VT + ((size_t)((b * H_ + h) * D_ + d)) * S_ + sbase) = o;
            }
        }
    }

    // ===== tile K -> kk in LDS =====
    {
        int n0 = 1024 + g * 256;
        const u16* gB = Wbf + (size_t)(n0 + srow) * K_ + scolE;
        f32x4 acc[8][4] = {};
        run_tile(gA, gB, lds, t16, aB, bB, pc0, pc1, acc);
        float bv[4];
#pragma unroll
        for (int ni = 0; ni < 4; ++ni) bv[ni] = bias[n0 + wc * 64 + ni * 16 + lr];
        // kk LDS: [head=wc][d][s], byte = wc*32768 + d*512 + (s*2 ^ ((d&7)<<4))
#pragma unroll
        for (int mi = 0; mi < 8; ++mi) {
            int sl0 = wr * 128 + mi * 16 + lg * 4;
            float mk[4];
#pragma unroll
            for (int j = 0; j < 4; ++j) mk[j] = mask[m0 + sl0 + j];
#pragma unroll
            for (int ni = 0; ni < 4; ++ni) {
                int d = ni * 16 + lr;
                u16x4 o;
#pragma unroll
                for (int j = 0; j < 4; ++j)
                    o[j] = f2b(phi_f((acc[mi][ni][j] + bv[ni]) * mk[j]));
                *(u16x4*)(lds + wc * 32768 + d * 512 + ((sl0 * 2) ^ ((d & 7) << 4))) = o;
            }
        }
    }
    __syncthreads();

    // ===== kv + ksum partials (kk from LDS, v from VT just written) =====
    {
        int head = wid & 3, mh = wid >> 2;
        int bh = b * 16 + g * 4 + head;
        f32x4 akv[2][4] = {};
        const u16* vbase = VT + ((size_t)(bh * 64 + mh * 32 + lr)) * S_ + s0;
#pragma unroll
        for (int ks = 0; ks < 8; ++ks) {
            bf16x8 vf[2];
#pragma unroll
            for (int mi = 0; mi < 2; ++mi)
                vf[mi] = *(const bf16x8*)(vbase + (size_t)mi * 16 * S_ + ks * 32 + lg * 8);
#pragma unroll
            for (int ni = 0; ni < 4; ++ni) {
                int dd = ni * 16 + lr;
                bf16x8 kf = *(const bf16x8*)(lds + head * 32768 + dd * 512 +
                                             ((ks * 64 + lg * 16) ^ ((dd & 7) << 4)));
                akv[0][ni] = __builtin_amdgcn_mfma_f32_16x16x32_bf16(vf[0], kf, akv[0][ni], 0, 0, 0);
                akv[1][ni] = __builtin_amdgcn_mfma_f32_16x16x32_bf16(vf[1], kf, akv[1][ni], 0, 0, 0);
            }
        }
        float* kvp = KVP + ((size_t)(tm & 15) * 64 + bh) * 4096;
#pragma unroll
        for (int mi = 0; mi < 2; ++mi)
#pragma unroll
            for (int ni = 0; ni < 4; ++ni)
#pragma unroll
                for (int j = 0; j < 4; ++j)
                    kvp[(mh * 32 + mi * 16 + lg * 4 + j) * 64 + ni * 16 + lr] = akv[mi][ni][j];
        int hd = t >> 7, dd2 = (t >> 1) & 63, hf = t & 1;
        float ksm = 0.f;
#pragma unroll
        for (int i = 0; i < 16; ++i) {
            bf16x8 kk8 = *(const bf16x8*)(lds + hd * 32768 + dd2 * 512 +
                                          ((hf * 256 + i * 16) ^ ((dd2 & 7) << 4)));
#pragma unroll
            for (int e = 0; e < 8; ++e) ksm += b2f((u16)kk8[e]);
        }
        ksm += __shfl_xor(ksm, 1);
        if (!hf) KSP[(tm & 15) * 4096 + (b * 16 + g * 4 + hd) * 64 + dd2] = ksm;
    }
}

// ---------------- kernel 3: reduce partials -> KVB bf16 [bh][80][64] pre-swizzled ----------------
__global__ void reduce_kvb(const float* __restrict__ KVP, const float* __restrict__ KSP,
                           u16* __restrict__ KVB)
{
    int bh = blockIdx.x;            // 64
    int t = threadIdx.x;            // 256
    int d = t & 63, mg = t >> 6;
#pragma unroll 1
    for (int i = 0; i < 16; ++i) {
        int m = mg * 16 + i;
        float s = 0.f;
#pragma unroll
        for (int c = 0; c < 16; ++c)
            s += KVP[((size_t)c * 64 + bh) * 4096 + m * 64 + d];
        KVB[((size_t)bh * 80 + m) * 64 + (d ^ ((m & 7) << 3))] = f2b(s);
    }
    if (mg == 0) {
        float s = 0.f;
#pragma unroll
        for (int c = 0; c < 16; ++c) s += KSP[c * 4096 + bh * 64 + d];
        KVB[((size_t)bh * 80 + 64) * 64 + d] = f2b(s);   // m=64 -> m&7==0
    }
    for (int m = 65 + mg; m < 80; m += 4)
        KVB[((size_t)bh * 80 + m) * 64 + (d ^ ((m & 7) << 3))] = 0;
}

// ---------------- kernel 4: Q GEMM + fused attention epilogue ----------------
// R7 lesson: acc[8][4] f32 (128 regs) stayed live across both attn rounds ->
// ~250 live regs vs 256 budget -> scratch spill (WRITE_SIZE 117MB vs 66).
// Fix: pack acc -> kq16[8][4] u16x4 (64 regs) right after phi; acc dies.
__global__ __launch_bounds__(512, 2) void gemm_qattn(
    const u16* __restrict__ Abf, const u16* __restrict__ Wbf,
    const float* __restrict__ bias, const u16* __restrict__ KVB,
    float* __restrict__ Out)
{
    __shared__ __align__(16) char lds[131072];

    int wg  = blockIdx.x;
    int xcd = wg & 7, ii = wg >> 3;
    int tm  = xcd * 8 + (ii >> 2);
    int g   = ii & 3;
    int m0  = tm << 8;
    int b   = tm >> 4;

    int t = threadIdx.x;
    int l = t & 63, wid = t >> 6;
    int wr = wid >> 2, wc = wid & 3;
    int lg = l >> 4, lr = l & 15;

    int srow  = t >> 3;
    int scolE = ((t & 7) ^ (srow & 7)) << 3;
    int t16   = t * 16;

    const u16* gA = Abf + (size_t)(m0 + srow) * K_ + scolE;
    const char* aB = lds + (wr * 128 + lr) * 128;
    const char* bB = lds + 32768 + (wc * 64 + lr) * 128;
    int pc0 = (lg * 16) ^ ((lr & 7) << 4);
    int pc1 = pc0 ^ 64;

    int n0 = g * 256;
    const u16* gB = Wbf + (size_t)(n0 + srow) * K_ + scolE;

    u16x4 kq16[8][4];
    {
        f32x4 acc[8][4] = {};
        run_tile(gA, gB, lds, t16, aB, bB, pc0, pc1, acc);

        // stage kv for 4 heads (40960 B) into lds[0..40960); overlaps phi VALU
        const u16* kvbg = KVB + (size_t)(b * 16 + g * 4) * 80 * 64;
#pragma unroll
        for (int i = 0; i < 5; ++i)
            gload16(kvbg + i * 4096 + t * 8, lds + i * 8192 + t16);

        float bv[4];
#pragma unroll
        for (int ni = 0; ni < 4; ++ni) bv[ni] = bias[n0 + wc * 64 + ni * 16 + lr];
        // pack NOW: acc (128 regs) dies here; kq16 is 64 regs
#pragma unroll
        for (int mi = 0; mi < 8; ++mi)
#pragma unroll
            for (int ni = 0; ni < 4; ++ni) {
                u16x4 o;
#pragma unroll
                for (int j = 0; j < 4; ++j)
                    o[j] = f2b(phi_f(acc[mi][ni][j] + bv[ni]));
                kq16[mi][ni] = o;
            }
    }
    VMCNT(0);
    __syncthreads();

    // two rounds of 128 s-rows: kq -> LDS [s_loc][head][d] at offset 40960
#pragma unroll
    for (int r = 0; r < 2; ++r) {
        __syncthreads();                  // prior round's reads complete
        if (wr == r) {
#pragma unroll
            for (int mi = 0; mi < 8; ++mi)
#pragma unroll
                for (int j = 0; j < 4; ++j) {
                    int sl = mi * 16 + lg * 4 + j;
                    int swz = (sl & 7) << 4;
#pragma unroll
                    for (int ni = 0; ni < 4; ++ni) {
                        int d2 = (ni * 16 + lr) * 2;
                        *(u16*)(lds + 40960 + sl * 512 + wc * 128 + (d2 ^ swz)) =
                            (u16)kq16[mi][ni][j];
                    }
                }
        }
        __syncthreads();

        f32x4 a2[4][5] = {};
#pragma unroll
        for (int kh = 0; kh < 2; ++kh) {
            bf16x8 af[4];
#pragma unroll
            for (int mi2 = 0; mi2 < 4; ++mi2) {
                int sl = wr * 64 + mi2 * 16 + lr;
                af[mi2] = *(const bf16x8*)(lds + 40960 + sl * 512 + wc * 128 +
                                           ((kh * 64 + lg * 16) ^ ((sl & 7) << 4)));
            }
#pragma unroll
            for (int ni2 = 0; ni2 < 5; ++ni2) {
                int m = ni2 * 16 + lr;
                bf16x8 bf_ = *(const bf16x8*)(lds + wc * 10240 + m * 128 +
                                              ((kh * 64 + lg * 16) ^ ((m & 7) << 4)));
#pragma unroll
                for (int mi2 = 0; mi2 < 4; ++mi2)
                    a2[mi2][ni2] = __builtin_amdgcn_mfma_f32_16x16x32_bf16(
                        af[mi2], bf_, a2[mi2][ni2], 0, 0, 0);
            }
        }
        // den (ksum column), divide, store fp32
#pragma unroll
        for (int mi2 = 0; mi2 < 4; ++mi2)
#pragma unroll
            for (int j = 0; j < 4; ++j) {
                float den = __shfl(a2[mi2][4][j], l & 48);
                float z = 1.f / (den + 1e-6f);
                int sg = (tm & 15) * 256 + r * 128 + wr * 64 + mi2 * 16 + lg * 4 + j;
                float* op = Out + ((size_t)b * S_ + sg) * E_ + g * 256 + wc * 64;
#pragma unroll
                for (int ni2 = 0; ni2 < 4; ++ni2)
                    op[ni2 * 16 + lr] = a2[mi2][ni2][j] * z;
            }
    }
}

extern "C" void kernel_launch(void* const* d_in, const int* in_sizes, int n_in,
                              void* d_out, int out_size, void* d_ws, size_t ws_size,
                              hipStream_t stream)
{
    const float* inputs = (const float*)d_in[0];
    const float* mask   = (const float*)d_in[1];
    const float* w_qkv  = (const float*)d_in[2];
    const float* b_qkv  = (const float*)d_in[3];

    u16* Abf = (u16*)d_ws;                          // 16777216 bf16 (32 MB)
    u16* Wbf = Abf + (size_t)M_ * K_;               // 3145728 bf16 (6 MB)
    float* KVP = (float*)(Wbf + (size_t)N_ * K_);   // 16*64*4096 f32 (16 MB)
    float* KSP = KVP + 16 * 64 * 4096;              // 16*4096 f32
    u16* KVB   = (u16*)(KSP + 16 * 4096);           // 64*80*64 bf16 (640 KB)

    // V^T lives in d_out (bf16, 32 MB), consumed inside gemm_vk only;
    // gemm_qattn overwrites d_out with the final fp32 output.
    u16* VT = (u16*)d_out;

    cvt_bf16<<<2048, 256, 0, stream>>>(inputs, Abf, M_ * K_ / 8);
    cvt_bf16<<<768, 256, 0, stream>>>(w_qkv, Wbf, N_ * K_ / 8);
    gemm_vk<<<256, 512, 0, stream>>>(Abf, Wbf, b_qkv, mask, VT, KVP, KSP);
    reduce_kvb<<<64, 256, 0, stream>>>(KVP, KSP, KVB);
    gemm_qattn<<<256, 512, 0, stream>>>(Abf, Wbf, b_qkv, KVB, (float*)d_out);
}